// Round 5
// baseline (197.263 us; speedup 1.0000x reference)
//
#include <hip/hip_runtime.h>
#include <cstdint>
#include <cmath>

// ---- d_ws layout (4-byte words) ----
// Thresholds are stored as negthr = -(thr+1):  pc <= thr  <=>  (pc + negthr) < 0
#define OFF_W1   0      // 32  u32: conv1 weight bits (27 bits: c*9+dy*3+dx)
#define OFF_T1   32     // 32  i32: conv1 negthr
#define OFF_W2   64     // 288 u32: conv2 weight bits [o][k] over 32 in-ch
#define OFF_T2   352    // 32  i32: conv2 negthr
#define OFF_W3   384    // 576 u32: conv3 weight bits [o][k]
#define OFF_T3   960    // 64  i32: conv3 negthr
#define OFF_WFC1 1024   // 256 u32: fc1 weight bits, 2 words per output (64 bits)
#define OFF_A4   1280   // 128 f32: h = clip(pc*a4 + c4, -1, 1)
#define OFF_C4   1408   // 128 f32
#define OFF_WF2  1536   // 256 f32: w_fc2 [2][128]
#define OFF_WF3  1792   // 512 f32: w_fc3 [4][128]
#define OFF_BN5  2304   // 4 f32: inv5[2], d5[2]
#define OFF_BN6  2308   // 8 f32: inv6[4], d6[4]

__device__ __forceinline__ int thr_neg(double nterms, double g, double b, double m, double v) {
    double inv = g / sqrt(v + 1e-5);
    double t = m - b / inv;                   // bit=1  <=>  c >= t   (inv > 0)
    double thr = floor((nterms - t) * 0.5);   // c = nterms - 2*pc  =>  pc <= thr
    if (thr < -2147000000.0) thr = -2147000000.0;
    if (thr >  2147000000.0) thr =  2147000000.0;
    return -((int)thr + 1);                   // sign(pc + negthr) == (pc <= thr)
}

// 5 blocks x 256 threads. Coalesced global->LDS staging, then bit-pack from LDS.
__global__ void k_prep(const float* __restrict__ w1, const float* __restrict__ w2,
                       const float* __restrict__ w3, const float* __restrict__ wfc1,
                       const float* __restrict__ wfc2, const float* __restrict__ wfc3,
                       const float* __restrict__ bn1, const float* __restrict__ bn2,
                       const float* __restrict__ bn3, const float* __restrict__ bn4,
                       const float* __restrict__ bn5, const float* __restrict__ bn6,
                       unsigned int* __restrict__ ws) {
    __shared__ float stage[9216];
    int t = threadIdx.x;
    int blk = blockIdx.x;
    float* wsf = (float*)ws;
    int*   wsi = (int*)ws;

    if (blk == 0) {
        for (int i = t; i < 864; i += 256) stage[i] = w1[i];
        __syncthreads();
        if (t < 32) {
            unsigned int bits = 0;
            for (int j = 0; j < 27; ++j) bits |= (stage[t*27+j] >= 0.f ? 1u : 0u) << j;
            ws[OFF_W1 + t] = bits;
            wsi[OFF_T1 + t] = thr_neg(27.0,  bn1[t], bn1[32+t], bn1[64+t], bn1[96+t]);
            wsi[OFF_T2 + t] = thr_neg(288.0, bn2[t], bn2[32+t], bn2[64+t], bn2[96+t]);
        }
        for (int i = t; i < 256; i += 256) wsf[OFF_WF2 + i] = wfc2[i];
        for (int i = t; i < 512; i += 256) wsf[OFF_WF3 + i] = wfc3[i];
        if (t < 2) {
            float g = bn5[t], b = bn5[2+t], m = bn5[4+t], v = bn5[6+t];
            float inv = g / sqrtf(v + 1e-5f);
            wsf[OFF_BN5 + t]     = inv;
            wsf[OFF_BN5 + 2 + t] = b - m * inv;
        }
        if (t >= 4 && t < 8) {
            int j = t - 4;
            float g = bn6[j], b = bn6[4+j], m = bn6[8+j], v = bn6[12+j];
            float inv = g / sqrtf(v + 1e-5f);
            wsf[OFF_BN6 + j]     = inv;
            wsf[OFF_BN6 + 4 + j] = b - m * inv;
        }
    } else if (blk == 1) {
        for (int i = t; i < 9216; i += 256) stage[i] = w2[i];
        __syncthreads();
        for (int idx = t; idx < 288; idx += 256) {
            int o = idx / 9, k = idx - o*9;
            unsigned int bits = 0;
            for (int i = 0; i < 32; ++i)
                bits |= (stage[(o*32+i)*9 + k] >= 0.f ? 1u : 0u) << i;
            ws[OFF_W2 + idx] = bits;
        }
    } else if (blk == 2 || blk == 3) {
        int base = (blk - 2) * 9216;
        for (int i = t; i < 9216; i += 256) stage[i] = w3[base + i];
        __syncthreads();
        for (int idx = t; idx < 288; idx += 256) {
            int o = idx / 9, k = idx - o*9;
            unsigned int bits = 0;
            for (int i = 0; i < 32; ++i)
                bits |= (stage[(o*32+i)*9 + k] >= 0.f ? 1u : 0u) << i;
            ws[OFF_W3 + base/32 + idx] = bits;   // base/32 = 0 or 288
        }
    } else {
        for (int i = t; i < 8192; i += 256) stage[i] = wfc1[i];
        __syncthreads();
        if (t < 128) {
            unsigned int lo = 0, hi = 0;
            for (int j = 0; j < 32; ++j) lo |= (stage[t*64+j]    >= 0.f ? 1u : 0u) << j;
            for (int j = 0; j < 32; ++j) hi |= (stage[t*64+32+j] >= 0.f ? 1u : 0u) << j;
            ws[OFF_WFC1 + 2*t]     = lo;
            ws[OFF_WFC1 + 2*t + 1] = hi;
            float g = bn4[t], b = bn4[128+t], m = bn4[256+t], v = bn4[384+t];
            float inv = g / sqrtf(v + 1e-5f);
            wsf[OFF_A4 + t] = -2.f * inv;                 // c = 64 - 2*pc
            wsf[OFF_C4 + t] = (64.f - m) * inv + b;
        }
        if (t >= 128 && t < 192) {
            int j = t - 128;
            wsi[OFF_T3 + j] = thr_neg(288.0, bn3[j], bn3[64+j], bn3[128+j], bn3[192+j]);
        }
    }
}

// 2 images per wave (interleaved for ILP), 4 waves per block = 8 images/block.
// Wave-private LDS slices; same-wave DS ordering -> wave_barrier (0-instr fence)
// instead of hardware barriers. __launch_bounds__(256,8) pins <=64 VGPR so the
// 18.7KB LDS block still gets 8 blocks/CU = 32 waves.
#define WSTRIDE 584   // 66 + 400 + 100 + 16, padded to even
#define AB(a,b) __builtin_amdgcn_alignbit(a, b, 31)
__global__ __launch_bounds__(256, 8) void k_main(const float* __restrict__ x,
                                                 const unsigned int* __restrict__ ws,
                                                 float* __restrict__ out, int B) {
    __shared__ unsigned int s_u[8 * WSTRIDE];

    const int tid = threadIdx.x & 63;
    const int wid = threadIdx.x >> 6;
    const int b0  = blockIdx.x * 8 + wid * 2;
    if (b0 >= B) return;   // wave-uniform exit
    const bool act1 = (b0 + 1 < B);
    const int  b1   = act1 ? b0 + 1 : b0;
    const float* wsf = (const float*)ws;
    const int*   wsi = (const int*)ws;

    unsigned int* in0 = s_u + (wid*2) * WSTRIDE;  // [66]
    unsigned int* in1 = in0 + WSTRIDE;
    unsigned int* c10 = in0 + 66;                 // [400]
    unsigned int* c11 = in1 + 66;
    unsigned int* pA0 = c10 + 400;                // [100]
    unsigned int* pA1 = c11 + 400;
    unsigned int* pB0 = pA0 + 100;                // [16]
    unsigned int* pB1 = pA1 + 100;

    // ---- pack input sign bits: bit k of row word = sign(elem k); final ~ makes
    // bit=1 <=> elem>=0. Bits 22..31 are junk but never read (window uses 0..21).
    for (int r = tid; r < 66; r += 64) {
        int c = r / 22, y = r - c*22;
        const uint2* p0 = (const uint2*)(x + ((size_t)b0*3 + c)*484 + (size_t)y*22);
        const uint2* p1 = (const uint2*)(x + ((size_t)b1*3 + c)*484 + (size_t)y*22);
        uint2 q0[11], q1[11];
        #pragma unroll
        for (int j = 0; j < 11; ++j) { q0[j] = p0[j]; q1[j] = p1[j]; }
        unsigned int s0 = 0, s1 = 0;
        #pragma unroll
        for (int j = 10; j >= 0; --j) {
            s0 = AB(s0, q0[j].y); s0 = AB(s0, q0[j].x);
            s1 = AB(s1, q1[j].y); s1 = AB(s1, q1[j].x);
        }
        in0[r] = ~s0;
        in1[r] = ~s1;
    }
    __builtin_amdgcn_wave_barrier();

    // ---- conv1 + BN sign ----
    for (int pos = tid; pos < 400; pos += 64) {
        int y = pos / 20, xx = pos - y*20;
        unsigned int g0 = 0, g1 = 0;
        #pragma unroll
        for (int c = 0; c < 3; ++c)
            #pragma unroll
            for (int dy = 0; dy < 3; ++dy) {
                g0 |= ((in0[c*22 + y + dy] >> xx) & 7u) << (c*9 + dy*3);
                g1 |= ((in1[c*22 + y + dy] >> xx) & 7u) << (c*9 + dy*3);
            }
        unsigned int w0 = 0, w1 = 0;
        #pragma unroll
        for (int o = 31; o >= 0; --o) {
            unsigned int wv = ws[OFF_W1 + o];
            int tv = wsi[OFF_T1 + o];
            unsigned int s0 = (unsigned int)(__popc(g0 ^ wv) + tv);
            unsigned int s1 = (unsigned int)(__popc(g1 ^ wv) + tv);
            w0 = AB(w0, s0);
            w1 = AB(w1, s1);
        }
        c10[pos] = w0;
        c11[pos] = w1;
    }
    __builtin_amdgcn_wave_barrier();

    // ---- maxpool1 == OR of sign bits ----
    for (int p = tid; p < 100; p += 64) {
        int py = p / 10, px = p - py*10;
        int base = (2*py)*20 + 2*px;
        pA0[p] = c10[base] | c10[base+1] | c10[base+20] | c10[base+21];
        pA1[p] = c11[base] | c11[base+1] | c11[base+20] | c11[base+21];
    }
    __builtin_amdgcn_wave_barrier();

    // ---- conv2 + BN sign + pool2 (lane = one of 8x8 positions) ----
    {
        int y = tid >> 3, xx = tid & 7;
        unsigned int a9[9], b9[9];
        #pragma unroll
        for (int dy = 0; dy < 3; ++dy)
            #pragma unroll
            for (int dx = 0; dx < 3; ++dx) {
                a9[dy*3+dx] = pA0[(y+dy)*10 + xx + dx];
                b9[dy*3+dx] = pA1[(y+dy)*10 + xx + dx];
            }
        unsigned int w0 = 0, w1 = 0;
        #pragma unroll
        for (int o = 31; o >= 0; --o) {
            int t2 = wsi[OFF_T2 + o];
            int s0 = t2, s1 = t2;
            #pragma unroll
            for (int k = 0; k < 9; ++k) {
                unsigned int wv = ws[OFF_W2 + o*9 + k];
                s0 += __popc(a9[k] ^ wv);
                s1 += __popc(b9[k] ^ wv);
            }
            w0 = AB(w0, (unsigned int)s0);
            w1 = AB(w1, (unsigned int)s1);
        }
        w0 |= __shfl_xor(w0, 1);  w1 |= __shfl_xor(w1, 1);   // pool x pairs
        w0 |= __shfl_xor(w0, 8);  w1 |= __shfl_xor(w1, 8);   // pool y pairs
        if ((tid & 9) == 0) {
            pB0[(y>>1)*4 + (xx>>1)] = w0;
            pB1[(y>>1)*4 + (xx>>1)] = w1;
        }
    }
    __builtin_amdgcn_wave_barrier();

    // ---- conv3 + BN sign + pool3 -> 64-bit feature via ballot (lane = och) ----
    // Sequential per image to bound VGPR (bb[16] reused).
    unsigned long long b3[2];
    {
        unsigned int w3r[9];
        #pragma unroll
        for (int k = 0; k < 9; ++k) w3r[k] = ws[OFF_W3 + tid*9 + k];
        int negt = wsi[OFF_T3 + tid];
        #pragma unroll
        for (int im = 0; im < 2; ++im) {
            const unsigned int* pb = im ? pB1 : pB0;
            unsigned int bb[16];
            #pragma unroll
            for (int i = 0; i < 16; ++i) bb[i] = pb[i];
            unsigned int oracc = 0;
            #pragma unroll
            for (int py = 0; py < 2; ++py)
                #pragma unroll
                for (int px = 0; px < 2; ++px) {
                    int s = negt;
                    #pragma unroll
                    for (int dy = 0; dy < 3; ++dy)
                        #pragma unroll
                        for (int dx = 0; dx < 3; ++dx)
                            s += __popc(bb[(py+dy)*4 + px + dx] ^ w3r[dy*3+dx]);
                    oracc |= (unsigned int)s;
                }
            b3[im] = __ballot((int)oracc < 0);
        }
    }

    // ---- fc1 in registers ----
    float h0a, h1a, h0b, h1b;
    {
        const unsigned long long* wfc1b = (const unsigned long long*)(ws + OFF_WFC1);
        unsigned long long wlo = wfc1b[tid], whi = wfc1b[tid + 64];
        float a4l = wsf[OFF_A4 + tid], c4l = wsf[OFF_C4 + tid];
        float a4h = wsf[OFF_A4 + tid + 64], c4h = wsf[OFF_C4 + tid + 64];
        float p0 = fmaf((float)__popcll(b3[0] ^ wlo), a4l, c4l);
        float p1 = fmaf((float)__popcll(b3[0] ^ whi), a4h, c4h);
        float p2 = fmaf((float)__popcll(b3[1] ^ wlo), a4l, c4l);
        float p3 = fmaf((float)__popcll(b3[1] ^ whi), a4h, c4h);
        h0a = fminf(1.f, fmaxf(-1.f, p0));
        h1a = fminf(1.f, fmaxf(-1.f, p1));
        h0b = fminf(1.f, fmaxf(-1.f, p2));
        h1b = fminf(1.f, fmaxf(-1.f, p3));
    }

    // ---- fc2 (softmax) / fc3 (BN), both images reduced together ----
    {
        float part[12];
        #pragma unroll
        for (int j = 0; j < 2; ++j) {
            float wl = wsf[OFF_WF2 + j*128 + tid], wh = wsf[OFF_WF2 + j*128 + 64 + tid];
            part[j]     = h0a * wl + h1a * wh;
            part[6 + j] = h0b * wl + h1b * wh;
        }
        #pragma unroll
        for (int j = 0; j < 4; ++j) {
            float wl = wsf[OFF_WF3 + j*128 + tid], wh = wsf[OFF_WF3 + j*128 + 64 + tid];
            part[2 + j]  = h0a * wl + h1a * wh;
            part[8 + j]  = h0b * wl + h1b * wh;
        }
        #pragma unroll
        for (int off = 32; off; off >>= 1) {
            #pragma unroll
            for (int j = 0; j < 12; ++j)
                part[j] += __shfl_xor(part[j], off);
        }
        if (tid < 6) {
            if (tid < 2) {
                float y0 = part[0]*wsf[OFF_BN5+0] + wsf[OFF_BN5+2];
                float y1 = part[1]*wsf[OFF_BN5+1] + wsf[OFF_BN5+3];
                float mx = fmaxf(y0, y1);
                float e0 = expf(y0 - mx), e1 = expf(y1 - mx);
                float r  = 1.f / (e0 + e1);
                out[(size_t)b0*2 + tid] = (tid == 0 ? e0 : e1) * r;
                if (act1) {
                    float z0 = part[6]*wsf[OFF_BN5+0] + wsf[OFF_BN5+2];
                    float z1 = part[7]*wsf[OFF_BN5+1] + wsf[OFF_BN5+3];
                    float mz = fmaxf(z0, z1);
                    float f0 = expf(z0 - mz), f1 = expf(z1 - mz);
                    float rz = 1.f / (f0 + f1);
                    out[(size_t)b1*2 + tid] = (tid == 0 ? f0 : f1) * rz;
                }
            } else {
                int j = tid - 2;
                out[(size_t)B*2 + (size_t)b0*4 + j] = part[2+j]*wsf[OFF_BN6+j] + wsf[OFF_BN6+4+j];
                if (act1)
                    out[(size_t)B*2 + (size_t)b1*4 + j] = part[8+j]*wsf[OFF_BN6+j] + wsf[OFF_BN6+4+j];
            }
        }
    }
}

extern "C" void kernel_launch(void* const* d_in, const int* in_sizes, int n_in,
                              void* d_out, int out_size, void* d_ws, size_t ws_size,
                              hipStream_t stream) {
    const float* x    = (const float*)d_in[0];
    const float* w1   = (const float*)d_in[1];
    const float* w2   = (const float*)d_in[2];
    const float* w3   = (const float*)d_in[3];
    const float* wfc1 = (const float*)d_in[4];
    const float* wfc2 = (const float*)d_in[5];
    const float* wfc3 = (const float*)d_in[6];
    const float* bn1  = (const float*)d_in[7];
    const float* bn2  = (const float*)d_in[8];
    const float* bn3  = (const float*)d_in[9];
    const float* bn4  = (const float*)d_in[10];
    const float* bn5  = (const float*)d_in[11];
    const float* bn6  = (const float*)d_in[12];
    unsigned int* ws  = (unsigned int*)d_ws;
    float* out        = (float*)d_out;
    int B = in_sizes[0] / 1452;   // 3*22*22

    k_prep<<<5, 256, 0, stream>>>(w1, w2, w3, wfc1, wfc2, wfc3,
                                  bn1, bn2, bn3, bn4, bn5, bn6, ws);
    k_main<<<(B + 7) / 8, 256, 0, stream>>>(x, ws, out, B);
}

// Round 6
// 193.121 us; speedup vs baseline: 1.0214x; 1.0214x over previous
//
#include <hip/hip_runtime.h>
#include <cstdint>
#include <cmath>

// ---- d_ws layout (4-byte words) ----
// Thresholds are stored as negthr = -(thr+1):  pc <= thr  <=>  (pc + negthr) < 0
#define OFF_W1   0      // 32  u32: conv1 weight bits (27 bits: c*9+dy*3+dx)
#define OFF_T1   32     // 32  i32: conv1 negthr
#define OFF_W2   64     // 288 u32: conv2 weight bits [o][k] over 32 in-ch
#define OFF_T2   352    // 32  i32: conv2 negthr
#define OFF_W3   384    // 576 u32: conv3 weight bits [o][k]
#define OFF_T3   960    // 64  i32: conv3 negthr
#define OFF_WFC1 1024   // 256 u32: fc1 weight bits, 2 words per output (64 bits)
#define OFF_A4   1280   // 128 f32: h = clip(pc*a4 + c4, -1, 1)
#define OFF_C4   1408   // 128 f32
#define OFF_WF2  1536   // 256 f32: w_fc2 [2][128]
#define OFF_WF3  1792   // 512 f32: w_fc3 [4][128]
#define OFF_BN5  2304   // 4 f32: inv5[2], d5[2]
#define OFF_BN6  2308   // 8 f32: inv6[4], d6[4]

__device__ __forceinline__ int thr_neg(double nterms, double g, double b, double m, double v) {
    double inv = g / sqrt(v + 1e-5);
    double t = m - b / inv;                   // bit=1  <=>  c >= t   (inv > 0)
    double thr = floor((nterms - t) * 0.5);   // c = nterms - 2*pc  =>  pc <= thr
    if (thr < -2147000000.0) thr = -2147000000.0;
    if (thr >  2147000000.0) thr =  2147000000.0;
    return -((int)thr + 1);                   // sign(pc + negthr) == (pc <= thr)
}

// 5 blocks x 256 threads. Coalesced global->LDS staging, then bit-pack from LDS.
__global__ void k_prep(const float* __restrict__ w1, const float* __restrict__ w2,
                       const float* __restrict__ w3, const float* __restrict__ wfc1,
                       const float* __restrict__ wfc2, const float* __restrict__ wfc3,
                       const float* __restrict__ bn1, const float* __restrict__ bn2,
                       const float* __restrict__ bn3, const float* __restrict__ bn4,
                       const float* __restrict__ bn5, const float* __restrict__ bn6,
                       unsigned int* __restrict__ ws) {
    __shared__ float stage[9216];
    int t = threadIdx.x;
    int blk = blockIdx.x;
    float* wsf = (float*)ws;
    int*   wsi = (int*)ws;

    if (blk == 0) {
        for (int i = t; i < 864; i += 256) stage[i] = w1[i];
        __syncthreads();
        if (t < 32) {
            unsigned int bits = 0;
            for (int j = 0; j < 27; ++j) bits |= (stage[t*27+j] >= 0.f ? 1u : 0u) << j;
            ws[OFF_W1 + t] = bits;
            wsi[OFF_T1 + t] = thr_neg(27.0,  bn1[t], bn1[32+t], bn1[64+t], bn1[96+t]);
            wsi[OFF_T2 + t] = thr_neg(288.0, bn2[t], bn2[32+t], bn2[64+t], bn2[96+t]);
        }
        for (int i = t; i < 256; i += 256) wsf[OFF_WF2 + i] = wfc2[i];
        for (int i = t; i < 512; i += 256) wsf[OFF_WF3 + i] = wfc3[i];
        if (t < 2) {
            float g = bn5[t], b = bn5[2+t], m = bn5[4+t], v = bn5[6+t];
            float inv = g / sqrtf(v + 1e-5f);
            wsf[OFF_BN5 + t]     = inv;
            wsf[OFF_BN5 + 2 + t] = b - m * inv;
        }
        if (t >= 4 && t < 8) {
            int j = t - 4;
            float g = bn6[j], b = bn6[4+j], m = bn6[8+j], v = bn6[12+j];
            float inv = g / sqrtf(v + 1e-5f);
            wsf[OFF_BN6 + j]     = inv;
            wsf[OFF_BN6 + 4 + j] = b - m * inv;
        }
    } else if (blk == 1) {
        for (int i = t; i < 9216; i += 256) stage[i] = w2[i];
        __syncthreads();
        for (int idx = t; idx < 288; idx += 256) {
            int o = idx / 9, k = idx - o*9;
            unsigned int bits = 0;
            for (int i = 0; i < 32; ++i)
                bits |= (stage[(o*32+i)*9 + k] >= 0.f ? 1u : 0u) << i;
            ws[OFF_W2 + idx] = bits;
        }
    } else if (blk == 2 || blk == 3) {
        int base = (blk - 2) * 9216;
        for (int i = t; i < 9216; i += 256) stage[i] = w3[base + i];
        __syncthreads();
        for (int idx = t; idx < 288; idx += 256) {
            int o = idx / 9, k = idx - o*9;
            unsigned int bits = 0;
            for (int i = 0; i < 32; ++i)
                bits |= (stage[(o*32+i)*9 + k] >= 0.f ? 1u : 0u) << i;
            ws[OFF_W3 + base/32 + idx] = bits;   // base/32 = 0 or 288
        }
    } else {
        for (int i = t; i < 8192; i += 256) stage[i] = wfc1[i];
        __syncthreads();
        if (t < 128) {
            unsigned int lo = 0, hi = 0;
            for (int j = 0; j < 32; ++j) lo |= (stage[t*64+j]    >= 0.f ? 1u : 0u) << j;
            for (int j = 0; j < 32; ++j) hi |= (stage[t*64+32+j] >= 0.f ? 1u : 0u) << j;
            ws[OFF_WFC1 + 2*t]     = lo;
            ws[OFF_WFC1 + 2*t + 1] = hi;
            float g = bn4[t], b = bn4[128+t], m = bn4[256+t], v = bn4[384+t];
            float inv = g / sqrtf(v + 1e-5f);
            wsf[OFF_A4 + t] = -2.f * inv;                 // c = 64 - 2*pc
            wsf[OFF_C4 + t] = (64.f - m) * inv + b;
        }
        if (t >= 128 && t < 192) {
            int j = t - 128;
            wsi[OFF_T3 + j] = thr_neg(288.0, bn3[j], bn3[64+j], bn3[128+j], bn3[192+j]);
        }
    }
}

// 2 images per wave (interleaved for ILP), 4 waves per block = 8 images/block.
// Wave-private LDS slices; same-wave DS ordering -> wave_barrier (0-instr fence)
// instead of hardware barriers. (256,8) pins <=64 VGPR; R5's uint2 staging
// arrays spilled to scratch under that cap (WRITE_SIZE 384KB->4.4MB) -- all
// register arrays here are kept small / single-image.
#define WSTRIDE 584   // 66 + 400 + 100 + 16, padded to even
#define AB(a,b) __builtin_amdgcn_alignbit(a, b, 31)
__global__ __launch_bounds__(256, 8) void k_main(const float* __restrict__ x,
                                                 const unsigned int* __restrict__ ws,
                                                 float* __restrict__ out, int B) {
    __shared__ unsigned int s_u[8 * WSTRIDE];

    const int tid = threadIdx.x & 63;
    const int wid = threadIdx.x >> 6;
    const int b0  = blockIdx.x * 8 + wid * 2;
    if (b0 >= B) return;   // wave-uniform exit
    const bool act1 = (b0 + 1 < B);
    const int  b1   = act1 ? b0 + 1 : b0;
    const float* wsf = (const float*)ws;
    const int*   wsi = (const int*)ws;

    unsigned int* in0 = s_u + (wid*2) * WSTRIDE;  // [66]
    unsigned int* in1 = in0 + WSTRIDE;
    unsigned int* c10 = in0 + 66;                 // [400]
    unsigned int* c11 = in1 + 66;
    unsigned int* pA0 = c10 + 400;                // [100]
    unsigned int* pA1 = c11 + 400;
    unsigned int* pB0 = pA0 + 100;                // [16]
    unsigned int* pB1 = pA1 + 100;

    // ---- pack input sign bits; one image per lane-task (132 tasks) to keep
    // live registers low. bit k = sign(elem k); final ~ -> bit=1 <=> elem>=0.
    for (int r = tid; r < 132; r += 64) {
        int im = (r >= 66);
        int rr = r - (im ? 66 : 0);
        int c = rr / 22, y = rr - c*22;
        int bsel = im ? b1 : b0;
        const uint2* p = (const uint2*)(x + ((size_t)bsel*3 + c)*484 + (size_t)y*22);
        unsigned int s = 0;
        #pragma unroll
        for (int j = 10; j >= 0; --j) {
            uint2 q = p[j];
            s = AB(s, q.y);
            s = AB(s, q.x);
        }
        (im ? in1 : in0)[rr] = ~s;
    }
    __builtin_amdgcn_wave_barrier();

    // ---- conv1 + BN sign: lane = (y, x-group of 7); 9 row words per image
    // loaded into registers ONCE, 7 x-positions slide over them. ----
    {
        int y = tid / 3;               // 0..21 (clamped); lanes 60..63 inactive
        int g3 = tid - y*3;
        if (y > 19) y = 19;
        const bool lact = (tid < 60);
        const int x0 = g3 * 7;
        unsigned int r0[9], r1[9];
        #pragma unroll
        for (int c = 0; c < 3; ++c)
            #pragma unroll
            for (int dy = 0; dy < 3; ++dy) {
                r0[c*3+dy] = in0[c*22 + y + dy];
                r1[c*3+dy] = in1[c*22 + y + dy];
            }
        #pragma unroll 1
        for (int i = 0; i < 7; ++i) {
            int xx = x0 + i;           // g3==2,i==6 -> xx==20 (dropped at store)
            unsigned int g0 = 0, g1 = 0;
            #pragma unroll
            for (int k = 0; k < 9; ++k) {
                g0 |= ((r0[k] >> xx) & 7u) << (k*3);
                g1 |= ((r1[k] >> xx) & 7u) << (k*3);
            }
            unsigned int w0 = 0, w1 = 0;
            #pragma unroll
            for (int o = 31; o >= 0; --o) {
                unsigned int wv = ws[OFF_W1 + o];
                int tv = wsi[OFF_T1 + o];
                unsigned int s0 = (unsigned int)(__popc(g0 ^ wv) + tv);
                unsigned int s1 = (unsigned int)(__popc(g1 ^ wv) + tv);
                w0 = AB(w0, s0);
                w1 = AB(w1, s1);
            }
            if (lact && xx < 20) {
                c10[y*20 + xx] = w0;
                c11[y*20 + xx] = w1;
            }
        }
    }
    __builtin_amdgcn_wave_barrier();

    // ---- maxpool1 == OR of sign bits ----
    for (int p = tid; p < 100; p += 64) {
        int py = p / 10, px = p - py*10;
        int base = (2*py)*20 + 2*px;
        pA0[p] = c10[base] | c10[base+1] | c10[base+20] | c10[base+21];
        pA1[p] = c11[base] | c11[base+1] | c11[base+20] | c11[base+21];
    }
    __builtin_amdgcn_wave_barrier();

    // ---- conv2 + BN sign + pool2 (lane = one of 8x8 positions) ----
    {
        int y = tid >> 3, xx = tid & 7;
        unsigned int a9[9], b9[9];
        #pragma unroll
        for (int dy = 0; dy < 3; ++dy)
            #pragma unroll
            for (int dx = 0; dx < 3; ++dx) {
                a9[dy*3+dx] = pA0[(y+dy)*10 + xx + dx];
                b9[dy*3+dx] = pA1[(y+dy)*10 + xx + dx];
            }
        unsigned int w0 = 0, w1 = 0;
        #pragma unroll
        for (int o = 31; o >= 0; --o) {
            int t2 = wsi[OFF_T2 + o];
            int s0 = t2, s1 = t2;
            #pragma unroll
            for (int k = 0; k < 9; ++k) {
                unsigned int wv = ws[OFF_W2 + o*9 + k];
                s0 += __popc(a9[k] ^ wv);
                s1 += __popc(b9[k] ^ wv);
            }
            w0 = AB(w0, (unsigned int)s0);
            w1 = AB(w1, (unsigned int)s1);
        }
        w0 |= __shfl_xor(w0, 1);  w1 |= __shfl_xor(w1, 1);   // pool x pairs
        w0 |= __shfl_xor(w0, 8);  w1 |= __shfl_xor(w1, 8);   // pool y pairs
        if ((tid & 9) == 0) {
            pB0[(y>>1)*4 + (xx>>1)] = w0;
            pB1[(y>>1)*4 + (xx>>1)] = w1;
        }
    }
    __builtin_amdgcn_wave_barrier();

    // ---- conv3 + BN sign + pool3 -> 64-bit feature via ballot (lane = och) ----
    // Sequential per image to bound VGPR (bb[16] reused).
    unsigned long long b3[2];
    {
        unsigned int w3r[9];
        #pragma unroll
        for (int k = 0; k < 9; ++k) w3r[k] = ws[OFF_W3 + tid*9 + k];
        int negt = wsi[OFF_T3 + tid];
        #pragma unroll
        for (int im = 0; im < 2; ++im) {
            const unsigned int* pb = im ? pB1 : pB0;
            unsigned int bb[16];
            #pragma unroll
            for (int i = 0; i < 16; ++i) bb[i] = pb[i];
            unsigned int oracc = 0;
            #pragma unroll
            for (int py = 0; py < 2; ++py)
                #pragma unroll
                for (int px = 0; px < 2; ++px) {
                    int s = negt;
                    #pragma unroll
                    for (int dy = 0; dy < 3; ++dy)
                        #pragma unroll
                        for (int dx = 0; dx < 3; ++dx)
                            s += __popc(bb[(py+dy)*4 + px + dx] ^ w3r[dy*3+dx]);
                    oracc |= (unsigned int)s;
                }
            b3[im] = __ballot((int)oracc < 0);
        }
    }

    // ---- fc1 in registers ----
    float h0a, h1a, h0b, h1b;
    {
        const unsigned long long* wfc1b = (const unsigned long long*)(ws + OFF_WFC1);
        unsigned long long wlo = wfc1b[tid], whi = wfc1b[tid + 64];
        float a4l = wsf[OFF_A4 + tid], c4l = wsf[OFF_C4 + tid];
        float a4h = wsf[OFF_A4 + tid + 64], c4h = wsf[OFF_C4 + tid + 64];
        float p0 = fmaf((float)__popcll(b3[0] ^ wlo), a4l, c4l);
        float p1 = fmaf((float)__popcll(b3[0] ^ whi), a4h, c4h);
        float p2 = fmaf((float)__popcll(b3[1] ^ wlo), a4l, c4l);
        float p3 = fmaf((float)__popcll(b3[1] ^ whi), a4h, c4h);
        h0a = fminf(1.f, fmaxf(-1.f, p0));
        h1a = fminf(1.f, fmaxf(-1.f, p1));
        h0b = fminf(1.f, fmaxf(-1.f, p2));
        h1b = fminf(1.f, fmaxf(-1.f, p3));
    }

    // ---- fc2 (softmax) / fc3 (BN), both images reduced together ----
    {
        float part[12];
        #pragma unroll
        for (int j = 0; j < 2; ++j) {
            float wl = wsf[OFF_WF2 + j*128 + tid], wh = wsf[OFF_WF2 + j*128 + 64 + tid];
            part[j]     = h0a * wl + h1a * wh;
            part[6 + j] = h0b * wl + h1b * wh;
        }
        #pragma unroll
        for (int j = 0; j < 4; ++j) {
            float wl = wsf[OFF_WF3 + j*128 + tid], wh = wsf[OFF_WF3 + j*128 + 64 + tid];
            part[2 + j]  = h0a * wl + h1a * wh;
            part[8 + j]  = h0b * wl + h1b * wh;
        }
        #pragma unroll
        for (int off = 32; off; off >>= 1) {
            #pragma unroll
            for (int j = 0; j < 12; ++j)
                part[j] += __shfl_xor(part[j], off);
        }
        if (tid < 6) {
            if (tid < 2) {
                float y0 = part[0]*wsf[OFF_BN5+0] + wsf[OFF_BN5+2];
                float y1 = part[1]*wsf[OFF_BN5+1] + wsf[OFF_BN5+3];
                float mx = fmaxf(y0, y1);
                float e0 = expf(y0 - mx), e1 = expf(y1 - mx);
                float r  = 1.f / (e0 + e1);
                out[(size_t)b0*2 + tid] = (tid == 0 ? e0 : e1) * r;
                if (act1) {
                    float z0 = part[6]*wsf[OFF_BN5+0] + wsf[OFF_BN5+2];
                    float z1 = part[7]*wsf[OFF_BN5+1] + wsf[OFF_BN5+3];
                    float mz = fmaxf(z0, z1);
                    float f0 = expf(z0 - mz), f1 = expf(z1 - mz);
                    float rz = 1.f / (f0 + f1);
                    out[(size_t)b1*2 + tid] = (tid == 0 ? f0 : f1) * rz;
                }
            } else {
                int j = tid - 2;
                out[(size_t)B*2 + (size_t)b0*4 + j] = part[2+j]*wsf[OFF_BN6+j] + wsf[OFF_BN6+4+j];
                if (act1)
                    out[(size_t)B*2 + (size_t)b1*4 + j] = part[8+j]*wsf[OFF_BN6+j] + wsf[OFF_BN6+4+j];
            }
        }
    }
}

extern "C" void kernel_launch(void* const* d_in, const int* in_sizes, int n_in,
                              void* d_out, int out_size, void* d_ws, size_t ws_size,
                              hipStream_t stream) {
    const float* x    = (const float*)d_in[0];
    const float* w1   = (const float*)d_in[1];
    const float* w2   = (const float*)d_in[2];
    const float* w3   = (const float*)d_in[3];
    const float* wfc1 = (const float*)d_in[4];
    const float* wfc2 = (const float*)d_in[5];
    const float* wfc3 = (const float*)d_in[6];
    const float* bn1  = (const float*)d_in[7];
    const float* bn2  = (const float*)d_in[8];
    const float* bn3  = (const float*)d_in[9];
    const float* bn4  = (const float*)d_in[10];
    const float* bn5  = (const float*)d_in[11];
    const float* bn6  = (const float*)d_in[12];
    unsigned int* ws  = (unsigned int*)d_ws;
    float* out        = (float*)d_out;
    int B = in_sizes[0] / 1452;   // 3*22*22

    k_prep<<<5, 256, 0, stream>>>(w1, w2, w3, wfc1, wfc2, wfc3,
                                  bn1, bn2, bn3, bn4, bn5, bn6, ws);
    k_main<<<(B + 7) / 8, 256, 0, stream>>>(x, ws, out, B);
}